// Round 6
// baseline (5348.802 us; speedup 1.0000x reference)
//
#include <hip/hip_runtime.h>

// ---------------------------------------------------------------------------
// 2-layer tanh SimpleRNN, BATCH=256, SEQ=80, UNITS=2048 (fp32 in/out).
// Round 6: B pinned in STATIC 128 KiB LDS as a direct __shared__ array
// (guaranteed ds_read -> lgkmcnt only; counted vmcnt A-pipeline stays exact).
// 256 WGs x 512 thr (1/CU): bid<128 = layer0 tile (N=16, K=2176),
// bid>=128 = layer1 tile (N=16, K=4096). Wave owns 32 batch rows, full K.
// h: per-timestep slots (no address reuse), sc0sc1 write-through stores,
// normal cached loads, fence-free global barrier (all r4-proven).
// ---------------------------------------------------------------------------

typedef _Float16 f16;
typedef _Float16 f16x2 __attribute__((ext_vector_type(2)));
typedef _Float16 f16x8 __attribute__((ext_vector_type(8)));
typedef float    f32x4 __attribute__((ext_vector_type(4)));

#define NWG    256
#define SEQ    80
#define EPAD   128
#define NKC0   68          // L0 K chunks: 2048 (U0) + 128 (x-pad) = 68*32
#define NKC1   128         // L1 K chunks: 4096 ([W1;U1])

// ---- workspace layout (bytes) ----
#define FLAGS_OFF   0
#define B0S_OFF     1024
#define B0S_SIZE    (8704 * 1024)            // 128 shards x 68 KiB
#define B1S_OFF     (B0S_OFF + B0S_SIZE)
#define B1S_SIZE    (16384 * 1024)           // 128 shards x 128 KiB
#define XP_OFF      (B1S_OFF + B1S_SIZE)
#define XP_SIZE     (SEQ * 256 * EPAD * 2)   // 5,242,880
#define H0_OFF      (XP_OFF + XP_SIZE)
#define HSLOT       (256 * 2048 * 2)         // 1 MiB per h slot
#define HSLOT_H     (256 * 2048)
#define WS_FULL     ((size_t)H0_OFF + (size_t)162 * HSLOT)
#define WS_MIN      ((size_t)H0_OFF + (size_t)6 * HSLOT)

__device__ __forceinline__ float tanh_fast(float x) {
  x = fminf(15.f, fmaxf(-15.f, x));
  float e = __expf(2.f * x);
  return (e - 1.f) * __builtin_amdgcn_rcpf(e + 1.f);
}

__device__ __forceinline__ f16x8 ldg16_coh(const f16* p) {   // bypass L1+L2
  f16x8 r;
  asm volatile("global_load_dwordx4 %0, %1, off sc0 sc1" : "=v"(r) : "v"(p));
  return r;
}
__device__ __forceinline__ f16x8 ldg16(const f16* p) {       // normal cached
  f16x8 r;
  asm volatile("global_load_dwordx4 %0, %1, off" : "=v"(r) : "v"(p));
  return r;
}
__device__ __forceinline__ void stg16_coh(f16* p, f16x8 v) { // write-through
  asm volatile("global_store_dwordx4 %0, %1, off sc0 sc1" :: "v"(p), "v"(v) : "memory");
}
__device__ __forceinline__ void stg2_coh(f16* p, f16 v) {    // 2B write-through
  unsigned int w = (unsigned int)__builtin_bit_cast(unsigned short, v);
  asm volatile("global_store_short %0, %1, off sc0 sc1" :: "v"(p), "v"(w) : "memory");
}
// counted waits on one pipeline stage's 2 A-frags; reg-tied vs hoisting
#define VWAIT(name, n)                                                        \
__device__ __forceinline__ void name(f16x8 (&a)[2]) {                         \
  asm volatile("s_waitcnt vmcnt(" #n ")"                                      \
    : "+v"(a[0]), "+v"(a[1]) :: "memory");                                    \
}
VWAIT(vwait6, 6)
VWAIT(vwait4, 4)
VWAIT(vwait2, 2)
VWAIT(vwait0, 0)

// device-wide barrier: vmcnt drain + relaxed agent flags; NO cache fences
__device__ __forceinline__ void gbar(int* flags, int target) {
  asm volatile("s_waitcnt vmcnt(0)" ::: "memory");
  __syncthreads();
  if (threadIdx.x == 0)
    __hip_atomic_store(&flags[blockIdx.x], target, __ATOMIC_RELAXED,
                       __HIP_MEMORY_SCOPE_AGENT);
  if (threadIdx.x < NWG) {
    while (__hip_atomic_load(&flags[threadIdx.x], __ATOMIC_RELAXED,
                             __HIP_MEMORY_SCOPE_AGENT) < target)
      __builtin_amdgcn_s_sleep(2);
  }
  __syncthreads();
}

// ---------------------------------------------------------------------------
// prologue 1: weights -> per-WG contiguous fragment shards (N=16 everywhere).
// L0 frag = slice*68 + kc  (slice = col/16, 128 slices)
// L1 frag = slice*128 + kc (128 slices)
// lane l holds (k = kc*32 + (l>>4)*8 + j, col = slice*16 + (l&15))
// ---------------------------------------------------------------------------
__global__ __launch_bounds__(256) void fmt_weights(
    const float* __restrict__ W0, const float* __restrict__ U0,
    const float* __restrict__ W1, const float* __restrict__ U1,
    char* __restrict__ ws)
{
  int frag = blockIdx.x * 4 + (threadIdx.x >> 6);
  int lane = threadIdx.x & 63, lr = lane & 15, lk = (lane >> 4) * 8;
  f16x8 h;
  f16* dst;
  if (frag < 128 * NKC0) {                     // L0: 8704 frags
    int slice = frag / NKC0, kc = frag % NKC0;
    int col = slice * 16 + lr;
#pragma unroll
    for (int j = 0; j < 8; ++j) {
      int k = kc * 32 + lk + j;
      float v;
      if (k < 2048) v = U0[(size_t)k * 2048 + col];
      else { int e = k - 2048; v = (e < 100) ? W0[(size_t)e * 2048 + col] : 0.f; }
      h[j] = (f16)v;
    }
    dst = (f16*)(ws + B0S_OFF) + (size_t)frag * 512;
  } else {                                     // L1: 16384 frags
    int g2 = frag - 128 * NKC0;
    int kc = g2 & 127;
    int col = (g2 >> 7) * 16 + lr;
#pragma unroll
    for (int j = 0; j < 8; ++j) {
      int k = kc * 32 + lk + j;
      float v = (k < 2048) ? W1[(size_t)k * 2048 + col]
                           : U1[(size_t)(k - 2048) * 2048 + col];
      h[j] = (f16)v;
    }
    dst = (f16*)(ws + B1S_OFF) + (size_t)g2 * 512;
  }
  *(f16x8*)(dst + lane * 8) = h;
}

// ---------------------------------------------------------------------------
// prologue 2: embedding lookup -> Xp[t][b][0..127] fp16 (cols >=100 zero)
// ---------------------------------------------------------------------------
__global__ __launch_bounds__(256) void embed_k(
    const int* __restrict__ inputs, const float* __restrict__ emb,
    char* __restrict__ ws)
{
  int r = blockIdx.x * 4 + (threadIdx.x >> 6);   // r = t*256 + b
  int lane = threadIdx.x & 63;
  int t = r >> 8, b = r & 255;
  int idx = inputs[b * SEQ + t];
  int e = lane * 2;
  f16x2 h;
  if (e < 100) {
    const float* src = emb + (size_t)idx * 100 + e;
    h[0] = (f16)src[0]; h[1] = (f16)src[1];
  } else { h[0] = (f16)0.f; h[1] = (f16)0.f; }
  *(f16x2*)(ws + XP_OFF + ((size_t)r * EPAD + e) * 2) = h;
}

// ---------------------------------------------------------------------------
// K-loop macro: 4-stage counted-vmcnt pipeline; 2 A-loads per stage; B from
// the __shared__ Bsh array (direct access => ds_read_b128, lgkmcnt only).
// NKC must be a multiple of 4. kc<64 reads A1+o1; kc>=64 reads A2+o2.
// ---------------------------------------------------------------------------
#define KLOOP(NKC, A1, A2, O1, O2)                                            \
  do {                                                                        \
    f16x8 A_[4][2];                                                           \
    auto LD = [&](int kc, f16x8 (&a)[2]) {                                    \
      _Pragma("unroll")                                                       \
      for (int mf = 0; mf < 2; ++mf) {                                        \
        const f16* p = (kc < 64) ? (A1) + (O1)[mf] + (size_t)kc * 32          \
                                 : (A2) + (O2)[mf] + (size_t)(kc - 64) * 32;  \
        if (COH) a[mf] = ldg16_coh(p); else a[mf] = ldg16(p);                 \
      }                                                                       \
    };                                                                        \
    auto STEP = [&](int kc, f16x8 (&a)[2]) {                                  \
      f16x8 b = Bsh[kc * 64 + lane];                                          \
      acc[0] = __builtin_amdgcn_mfma_f32_16x16x32_f16(a[0], b, acc[0], 0, 0, 0); \
      acc[1] = __builtin_amdgcn_mfma_f32_16x16x32_f16(a[1], b, acc[1], 0, 0, 0); \
    };                                                                        \
    LD(0, A_[0]); LD(1, A_[1]); LD(2, A_[2]);                                 \
    for (int kq = 0; kq < (NKC) / 4 - 1; ++kq) {                              \
      const int k0 = kq * 4;                                                  \
      LD(k0 + 3, A_[3]); vwait6(A_[0]); STEP(k0 + 0, A_[0]);                  \
      LD(k0 + 4, A_[0]); vwait6(A_[1]); STEP(k0 + 1, A_[1]);                  \
      LD(k0 + 5, A_[1]); vwait6(A_[2]); STEP(k0 + 2, A_[2]);                  \
      LD(k0 + 6, A_[2]); vwait6(A_[3]); STEP(k0 + 3, A_[3]);                  \
    }                                                                         \
    LD((NKC) - 1, A_[3]);                                                     \
    vwait6(A_[0]); STEP((NKC) - 4, A_[0]);                                    \
    vwait4(A_[1]); STEP((NKC) - 3, A_[1]);                                    \
    vwait2(A_[2]); STEP((NKC) - 2, A_[2]);                                    \
    vwait0(A_[3]); STEP((NKC) - 1, A_[3]);                                    \
  } while (0)

// ---------------------------------------------------------------------------
// persistent RNN kernel. bid<128: L0 (cols bid*16, K=2176); bid>=128: L1
// (cols (bid-128)*16, K=4096). 8 waves x 32 rows each, full K per wave.
// phase p: L0 -> h0[p] (p<80); L1 -> h1[p-1] (zeros at p=0).
// ---------------------------------------------------------------------------
template <int NBUF, bool COH>
__global__ __launch_bounds__(512, 1) void rnn_persist(
    const float* __restrict__ b0v, const float* __restrict__ b1v,
    char* __restrict__ ws)
{
  __shared__ f16x8 Bsh[8192];                    // 128 KiB pinned B shard

  const int bid = blockIdx.x;
  const int tid = threadIdx.x;
  const int wv = tid >> 6, lane = tid & 63;
  const int lr = lane & 15, lk = (lane >> 4) * 8;

  int* flags = (int*)(ws + FLAGS_OFF);
  f16* H0b = (f16*)(ws + H0_OFF);
  f16* H1b = H0b + (size_t)NBUF * HSLOT_H;
  const f16* Xp = (const f16*)(ws + XP_OFF);

  const bool isL0 = bid < 128;
  const int n0 = (isL0 ? bid : bid - 128) * 16;
  const float* bias = isL0 ? b0v : b1v;

  // ---- stage this WG's B shard into LDS (once; plain load -> ds_write) ----
  {
    const f16x8* src = (const f16x8*)(isL0
        ? ws + B0S_OFF + (size_t)bid * (NKC0 * 1024)
        : ws + B1S_OFF + (size_t)(bid - 128) * (NKC1 * 1024));
    const int nfr = (isL0 ? NKC0 : NKC1) * 64;     // f16x8 elements
    for (int i = tid; i < nfr; i += 512) Bsh[i] = src[i];
    asm volatile("s_waitcnt vmcnt(0)" ::: "memory");
    __syncthreads();
  }

  // A-row offsets (elements): wave owns rows wv*32 .. wv*32+31
  size_t o1[2], xoff[2];
#pragma unroll
  for (int mf = 0; mf < 2; ++mf)
    o1[mf] = (size_t)(wv * 32 + mf * 16 + lr) * 2048 + lk;

  for (int p = 0; p <= 80; ++p) {
    const f16* Hr0 = H0b + (size_t)(p % NBUF) * HSLOT_H;                      // h0[p-1]
    const f16* Hr1 = H1b + (size_t)((p >= 1 ? (p - 1) % NBUF : 0)) * HSLOT_H; // h1[p-2]
    f16* Hw = isL0 ? H0b + (size_t)((p + 1) % NBUF) * HSLOT_H
                   : H1b + (size_t)(p % NBUF) * HSLOT_H;
    const bool active = isL0 ? (p < 80) : true;
    const bool fzero  = (!isL0) && (p == 0);

    if (active) {
      f32x4 acc[2];
      acc[0] = {0.f, 0.f, 0.f, 0.f};
      acc[1] = {0.f, 0.f, 0.f, 0.f};

      if (!fzero) {
        if (isL0) {
#pragma unroll
          for (int mf = 0; mf < 2; ++mf)
            xoff[mf] = ((size_t)p * 256 + wv * 32 + mf * 16 + lr) * EPAD + lk;
          KLOOP(NKC0, Hr0, Xp, o1, xoff);          // h0@U0 then x@W0
        } else {
          KLOOP(NKC1, Hr0, Hr1, o1, o1);           // h0@W1 then h1@U1
        }
      }

      // epilogue: bias + tanh, scalar sc0sc1 stores (col = n0+lr per lane)
      const float bv = bias[n0 + lr];
#pragma unroll
      for (int mf = 0; mf < 2; ++mf) {
        const int rb = wv * 32 + mf * 16 + (lane >> 4) * 4;
#pragma unroll
        for (int r = 0; r < 4; ++r) {
          f16 hv = fzero ? (f16)0.f : (f16)tanh_fast(acc[mf][r] + bv);
          stg2_coh(Hw + (size_t)(rb + r) * 2048 + n0 + lr, hv);
        }
      }
    }
    if (p < 80) gbar(flags, p + 1);
  }
}

// ---------------------------------------------------------------------------
// epilogue: logits = sigmoid(h1[79] @ Wo + bo) -> 256 fp32
// ---------------------------------------------------------------------------
__global__ __launch_bounds__(256) void logits_k(
    const f16* __restrict__ h1, const float* __restrict__ Wo,
    const float* __restrict__ bo, float* __restrict__ out)
{
  int row = blockIdx.x * 4 + (threadIdx.x >> 6);
  int lane = threadIdx.x & 63;
  const f16* hr = h1 + (size_t)row * 2048;
  float s = 0.f;
#pragma unroll
  for (int it = 0; it < 4; ++it) {
    int k = it * 512 + lane * 8;
    f16x8 hv = *(const f16x8*)(hr + k);
    const float4* wp = (const float4*)(Wo + k);
    float4 w0 = wp[0], w1 = wp[1];
    s += (float)hv[0] * w0.x + (float)hv[1] * w0.y + (float)hv[2] * w0.z + (float)hv[3] * w0.w;
    s += (float)hv[4] * w1.x + (float)hv[5] * w1.y + (float)hv[6] * w1.z + (float)hv[7] * w1.w;
  }
#pragma unroll
  for (int off = 32; off > 0; off >>= 1) s += __shfl_down(s, off);
  if (lane == 0) out[row] = 1.f / (1.f + __expf(-(s + bo[0])));
}

// ---------------------------------------------------------------------------
extern "C" void kernel_launch(void* const* d_in, const int* in_sizes, int n_in,
                              void* d_out, int out_size, void* d_ws, size_t ws_size,
                              hipStream_t stream)
{
  (void)in_sizes; (void)n_in; (void)out_size;
  const int*   inputs = (const int*)d_in[0];
  const float* emb    = (const float*)d_in[1];
  const float* W0     = (const float*)d_in[2];
  const float* U0     = (const float*)d_in[3];
  const float* b0     = (const float*)d_in[4];
  const float* W1     = (const float*)d_in[5];
  const float* U1     = (const float*)d_in[6];
  const float* b1     = (const float*)d_in[7];
  const float* Wo     = (const float*)d_in[8];
  const float* bo     = (const float*)d_in[9];
  char* ws = (char*)d_ws;
  if (ws_size < WS_MIN) return;   // visible validation failure if too small

  const bool full = (ws_size >= WS_FULL);
  const int  nbuf = full ? 81 : 3;

  // zero barrier flags + the two t=-1 init slots (slot 0 of H0 and H1)
  hipMemsetAsync(ws + FLAGS_OFF, 0, 1024, stream);
  hipMemsetAsync(ws + H0_OFF, 0, HSLOT, stream);
  hipMemsetAsync(ws + H0_OFF + (size_t)nbuf * HSLOT, 0, HSLOT, stream);

  fmt_weights<<<6272, 256, 0, stream>>>(W0, U0, W1, U1, ws);
  embed_k<<<5120, 256, 0, stream>>>(inputs, emb, ws);
  if (full) rnn_persist<81, false><<<NWG, 512, 0, stream>>>(b0, b1, ws);
  else      rnn_persist<3,  true ><<<NWG, 512, 0, stream>>>(b0, b1, ws);

  const f16* h1f = (const f16*)(ws + H0_OFF) + (size_t)nbuf * HSLOT_H
                   + (size_t)(80 % nbuf) * HSLOT_H;
  logits_k<<<64, 256, 0, stream>>>(h1f, Wo, bo, (float*)d_out);
}

// Round 7
// 3187.844 us; speedup vs baseline: 1.6779x; 1.6779x over previous
//
#include <hip/hip_runtime.h>

// ---------------------------------------------------------------------------
// 2-layer tanh SimpleRNN, BATCH=256, SEQ=80, UNITS=2048 (fp32 in/out).
// Round 7: c=32 col-slices, K split across WG PAIRS (B-shard <=128KiB LDS,
// pinned once). 256 WGs x 512thr (1/CU): bid<128 L0 (slice=bid>>1, half=bid&1,
// K-half=1088), bid>=128 L1 (K-half=2048; half0=W1/h0, half1=U1/h1).
// Wave = 32 rows x 32 cols x K-half, depth-6 counted-vmcnt A pipeline.
// Pair combine: 16KB fp32 partial exchange via sc1 bufs + monotone flags.
// h: per-timestep slots (cached loads), sc0sc1 write-through stores,
// fence-free global barrier (r4/r6-proven machinery).
// ---------------------------------------------------------------------------

typedef _Float16 f16;
typedef _Float16 f16x2 __attribute__((ext_vector_type(2)));
typedef _Float16 f16x8 __attribute__((ext_vector_type(8)));
typedef float    f32x4 __attribute__((ext_vector_type(4)));

#define NWG    256
#define SEQ    80
#define EPAD   128
#define NKC0H  34          // L0 K-half chunks (1088 = 34*32)
#define NKC1H  64          // L1 K-half chunks (2048 = 64*32)
#define SPL0   30          // L0 half1: kc>=30 -> Xp tail (960 U0 + 128 Xp)

// ---- workspace layout (bytes) ----
#define FLAGS_OFF   0                        // [0..255] gbar flags
#define FLAGS2_OFF  4096                     // [0..255] pair flags
#define B0S_OFF     8192
#define B0S_SIZE    (8704 * 1024)            // 128 shards x 68 KiB
#define B1S_OFF     (B0S_OFF + B0S_SIZE)
#define B1S_SIZE    (16384 * 1024)           // 128 shards x 128 KiB
#define XP_OFF      (B1S_OFF + B1S_SIZE)
#define XP_SIZE     (SEQ * 256 * EPAD * 2)
#define PB_OFF      (XP_OFF + XP_SIZE)       // pair bufs: 256 x 16 KiB
#define PB_SIZE     (256 * 16384)
#define H0_OFF      (PB_OFF + PB_SIZE)
#define HSLOT       (256 * 2048 * 2)         // 1 MiB per h slot
#define HSLOT_H     (256 * 2048)
#define WS_FULL     ((size_t)H0_OFF + (size_t)162 * HSLOT)
#define WS_MIN      ((size_t)H0_OFF + (size_t)6 * HSLOT)

__device__ __forceinline__ float tanh_fast(float x) {
  x = fminf(15.f, fmaxf(-15.f, x));
  float e = __expf(2.f * x);
  return (e - 1.f) * __builtin_amdgcn_rcpf(e + 1.f);
}

__device__ __forceinline__ f16x8 ldg16_coh(const f16* p) {   // bypass L1+L2
  f16x8 r;
  asm volatile("global_load_dwordx4 %0, %1, off sc0 sc1" : "=v"(r) : "v"(p));
  return r;
}
__device__ __forceinline__ f16x8 ldg16(const f16* p) {       // normal cached
  f16x8 r;
  asm volatile("global_load_dwordx4 %0, %1, off" : "=v"(r) : "v"(p));
  return r;
}
__device__ __forceinline__ f32x4 ldg16f_coh(const float* p) { // ordered (combine)
  f32x4 r;
  asm volatile("global_load_dwordx4 %0, %1, off sc0 sc1" : "=v"(r) : "v"(p) : "memory");
  return r;
}
__device__ __forceinline__ void stg16f_coh(float* p, f32x4 v) {
  asm volatile("global_store_dwordx4 %0, %1, off sc0 sc1" :: "v"(p), "v"(v) : "memory");
}
__device__ __forceinline__ void stg2_coh(f16* p, f16 v) {
  unsigned int w = (unsigned int)__builtin_bit_cast(unsigned short, v);
  asm volatile("global_store_short %0, %1, off sc0 sc1" :: "v"(p), "v"(w) : "memory");
}
// counted waits on one stage's 2 A-frags (reg-tied vs hoisting)
#define VWAIT(name, n)                                                        \
__device__ __forceinline__ void name(f16x8 (&a)[2]) {                         \
  asm volatile("s_waitcnt vmcnt(" #n ")"                                      \
    : "+v"(a[0]), "+v"(a[1]) :: "memory");                                    \
}
VWAIT(vw10, 10) VWAIT(vw8, 8) VWAIT(vw6, 6) VWAIT(vw4, 4) VWAIT(vw2, 2) VWAIT(vw0, 0)
// wait for combine partial loads (4 f32x4 tied)
__device__ __forceinline__ void vwp0(f32x4& a, f32x4& b, f32x4& c, f32x4& d) {
  asm volatile("s_waitcnt vmcnt(0)" : "+v"(a), "+v"(b), "+v"(c), "+v"(d) :: "memory");
}
__device__ __forceinline__ void vdrain() {
  asm volatile("s_waitcnt vmcnt(0)" ::: "memory");
}

// device-wide barrier: vmcnt drain + relaxed agent flags; NO cache fences
__device__ __forceinline__ void gbar(int* flags, int target) {
  vdrain();
  __syncthreads();
  if (threadIdx.x == 0)
    __hip_atomic_store(&flags[blockIdx.x], target, __ATOMIC_RELAXED,
                       __HIP_MEMORY_SCOPE_AGENT);
  if (threadIdx.x < NWG) {
    while (__hip_atomic_load(&flags[threadIdx.x], __ATOMIC_RELAXED,
                             __HIP_MEMORY_SCOPE_AGENT) < target)
      __builtin_amdgcn_s_sleep(2);
  }
  __syncthreads();
}

#define MFMA16(a, b, c) __builtin_amdgcn_mfma_f32_16x16x32_f16(a, b, c, 0, 0, 0)

// ---------------------------------------------------------------------------
// prologue 1: weights -> per-WG contiguous fragment shards.
// L0: gfrag = slice*136 + half*68 + kc*2 + nf   (shard base = bid*68 KiB)
// L1: gfrag = slice*256 + half*128 + kc*2 + nf  (shard base = (bid-128)*128 KiB)
// lane l: (k_local = kc*32 + (l>>4)*8 + j, col = slice*32 + nf*16 + (l&15))
// ---------------------------------------------------------------------------
__global__ __launch_bounds__(256) void fmt_weights(
    const float* __restrict__ W0, const float* __restrict__ U0,
    const float* __restrict__ W1, const float* __restrict__ U1,
    char* __restrict__ ws)
{
  int frag = blockIdx.x * 4 + (threadIdx.x >> 6);
  int lane = threadIdx.x & 63, lr = lane & 15, lk = (lane >> 4) * 8;
  f16x8 h;
  f16* dst;
  if (frag < 128 * 68) {                       // L0: 8704 frags
    int slice = frag / 136, rem = frag % 136;
    int half = rem / 68, rem2 = rem % 68;
    int kc = rem2 >> 1, nf = rem2 & 1;
    int col = slice * 32 + nf * 16 + lr;
#pragma unroll
    for (int j = 0; j < 8; ++j) {
      int kg = half * 1088 + kc * 32 + lk + j;
      float v;
      if (kg < 2048) v = U0[(size_t)kg * 2048 + col];
      else { int e = kg - 2048; v = (e < 100) ? W0[(size_t)e * 2048 + col] : 0.f; }
      h[j] = (f16)v;
    }
    dst = (f16*)(ws + B0S_OFF) + (size_t)frag * 512;
  } else {                                     // L1: 16384 frags
    int g2 = frag - 8704;
    int slice = g2 >> 8, rem = g2 & 255;
    int half = rem >> 7, rem2 = rem & 127;
    int kc = rem2 >> 1, nf = rem2 & 1;
    int col = slice * 32 + nf * 16 + lr;
#pragma unroll
    for (int j = 0; j < 8; ++j) {
      int kg = half * 2048 + kc * 32 + lk + j;
      float v = (kg < 2048) ? W1[(size_t)kg * 2048 + col]
                            : U1[(size_t)(kg - 2048) * 2048 + col];
      h[j] = (f16)v;
    }
    dst = (f16*)(ws + B1S_OFF) + (size_t)g2 * 512;
  }
  *(f16x8*)(dst + lane * 8) = h;
}

// ---------------------------------------------------------------------------
// prologue 2: embedding lookup -> Xp[t][b][0..127] fp16 (cols >=100 zero)
// ---------------------------------------------------------------------------
__global__ __launch_bounds__(256) void embed_k(
    const int* __restrict__ inputs, const float* __restrict__ emb,
    char* __restrict__ ws)
{
  int r = blockIdx.x * 4 + (threadIdx.x >> 6);   // r = t*256 + b
  int lane = threadIdx.x & 63;
  int t = r >> 8, b = r & 255;
  int idx = inputs[b * SEQ + t];
  int e = lane * 2;
  f16x2 h;
  if (e < 100) {
    const float* src = emb + (size_t)idx * 100 + e;
    h[0] = (f16)src[0]; h[1] = (f16)src[1];
  } else { h[0] = (f16)0.f; h[1] = (f16)0.f; }
  *(f16x2*)(ws + XP_OFF + ((size_t)r * EPAD + e) * 2) = h;
}

// ---------------------------------------------------------------------------
// K-half loop: depth-6 counted-vmcnt pipeline (12 outstanding A-loads),
// 2 A-loads + 2 LDS B-frags + 4 MFMA per step. NKC % 6 == 4 required.
// kc<SPLIT: A1+o1 (+kc*32); kc>=SPLIT: A2+o2 (+(kc-SPLIT)*32).
// ---------------------------------------------------------------------------
template <int NKC, int SPLIT, bool COH>
__device__ __forceinline__ void kloop(
    const f16* __restrict__ A1, const f16* __restrict__ A2,
    const size_t* o1, const size_t* o2,
    const f16x8* __restrict__ Bsh, int lane, f32x4 (&acc)[2][2])
{
  static_assert(NKC % 6 == 4, "tail shape requires NKC % 6 == 4");
  constexpr int Q = (NKC - 10) / 6;
  f16x8 A_[6][2];
  auto LD = [&](int kc, f16x8 (&a)[2]) {
#pragma unroll
    for (int mf = 0; mf < 2; ++mf) {
      const f16* p;
      if constexpr (SPLIT >= NKC) p = A1 + o1[mf] + (size_t)kc * 32;
      else p = (kc < SPLIT) ? A1 + o1[mf] + (size_t)kc * 32
                            : A2 + o2[mf] + (size_t)(kc - SPLIT) * 32;
      if (COH) a[mf] = ldg16_coh(p); else a[mf] = ldg16(p);
    }
  };
  auto STEP = [&](int kc, f16x8 (&a)[2]) {
    f16x8 b0 = Bsh[(kc * 2 + 0) * 64 + lane];
    f16x8 b1 = Bsh[(kc * 2 + 1) * 64 + lane];
    acc[0][0] = MFMA16(a[0], b0, acc[0][0]);
    acc[1][0] = MFMA16(a[1], b0, acc[1][0]);
    acc[0][1] = MFMA16(a[0], b1, acc[0][1]);
    acc[1][1] = MFMA16(a[1], b1, acc[1][1]);
  };

  LD(0, A_[0]); LD(1, A_[1]); LD(2, A_[2]); LD(3, A_[3]); LD(4, A_[4]);
  for (int q = 0; q < Q; ++q) {
    const int k0 = q * 6;
    LD(k0 + 5,  A_[5]); vw10(A_[0]); STEP(k0 + 0, A_[0]);
    LD(k0 + 6,  A_[0]); vw10(A_[1]); STEP(k0 + 1, A_[1]);
    LD(k0 + 7,  A_[1]); vw10(A_[2]); STEP(k0 + 2, A_[2]);
    LD(k0 + 8,  A_[2]); vw10(A_[3]); STEP(k0 + 3, A_[3]);
    LD(k0 + 9,  A_[3]); vw10(A_[4]); STEP(k0 + 4, A_[4]);
    LD(k0 + 10, A_[4]); vw10(A_[5]); STEP(k0 + 5, A_[5]);
  }
  const int t0 = Q * 6;
  LD(t0 + 5, A_[5]); vw10(A_[0]); STEP(t0 + 0, A_[0]);
  LD(t0 + 6, A_[0]); vw10(A_[1]); STEP(t0 + 1, A_[1]);
  LD(t0 + 7, A_[1]); vw10(A_[2]); STEP(t0 + 2, A_[2]);
  LD(t0 + 8, A_[2]); vw10(A_[3]); STEP(t0 + 3, A_[3]);
  LD(t0 + 9, A_[3]); vw10(A_[4]); STEP(t0 + 4, A_[4]);
  vw8(A_[5]); STEP(t0 + 5, A_[5]);
  vw6(A_[0]); STEP(t0 + 6, A_[0]);
  vw4(A_[1]); STEP(t0 + 7, A_[1]);
  vw2(A_[2]); STEP(t0 + 8, A_[2]);
  vw0(A_[3]); STEP(t0 + 9, A_[3]);
}

// ---------------------------------------------------------------------------
// persistent RNN kernel.
// half0 WG finishes rows 0-127 (waves 0-3 combine; waves 4-7 write partials);
// half1 WG finishes rows 128-255 (waves 4-7 combine; waves 0-3 write).
// ---------------------------------------------------------------------------
template <int NBUF, bool COH>
__global__ __launch_bounds__(512, 1) void rnn_persist(
    const float* __restrict__ b0v, const float* __restrict__ b1v,
    char* __restrict__ ws)
{
  __shared__ f16x8 Bsh[8192];                    // 128 KiB pinned B K-half shard

  const int bid = blockIdx.x;
  const int tid = threadIdx.x;
  const int wv = tid >> 6, lane = tid & 63;
  const int lr = lane & 15, lk = (lane >> 4) * 8;
  const int hi = lane >> 4;                      // 0..3 (C-frag row group)
  const int wvh = wv & 3;

  int* flags  = (int*)(ws + FLAGS_OFF);
  int* flags2 = (int*)(ws + FLAGS2_OFF);
  f16* H0b = (f16*)(ws + H0_OFF);
  f16* H1b = H0b + (size_t)NBUF * HSLOT_H;
  const f16* Xp = (const f16*)(ws + XP_OFF);

  const bool isL0 = bid < 128;
  const int u = isL0 ? bid : bid - 128;
  const int slice = u >> 1, half = u & 1;
  const int n0 = slice * 32;
  const float* bias = isL0 ? b0v : b1v;
  const bool iswriter = (wv >= 4) == (half == 0);
  float* mybuf = (float*)(ws + PB_OFF + (size_t)bid * 16384);
  const float* pbuf = (const float*)(ws + PB_OFF + (size_t)(bid ^ 1) * 16384);

  // ---- stage this WG's B shard into LDS once (plain loads -> ds_write) ----
  {
    const f16x8* src = (const f16x8*)(isL0
        ? ws + B0S_OFF + (size_t)u * (NKC0H * 2048)
        : ws + B1S_OFF + (size_t)u * (NKC1H * 2048));
    const int nfr = (isL0 ? NKC0H : NKC1H) * 128;
    for (int i = tid; i < nfr; i += 512) Bsh[i] = src[i];
    vdrain();
    __syncthreads();
  }

  size_t o1[2], xo[2];
#pragma unroll
  for (int mf = 0; mf < 2; ++mf)
    o1[mf] = (size_t)(wv * 32 + mf * 16 + lr) * 2048 + lk;

  for (int p = 0; p <= 80; ++p) {
    const f16* Hr0 = H0b + (size_t)(p % NBUF) * HSLOT_H;                      // h0[p-1]
    const f16* Hr1 = H1b + (size_t)((p >= 1 ? (p - 1) % NBUF : 0)) * HSLOT_H; // h1[p-2]
    f16* Hw = isL0 ? H0b + (size_t)((p + 1) % NBUF) * HSLOT_H
                   : H1b + (size_t)(p % NBUF) * HSLOT_H;
    const bool active = isL0 ? (p < 80) : true;
    const bool fzero  = (!isL0) && (p == 0);

    if (active) {
      if (!fzero) {
        f32x4 acc[2][2];
#pragma unroll
        for (int a = 0; a < 2; ++a)
#pragma unroll
          for (int b = 0; b < 2; ++b) acc[a][b] = {0.f, 0.f, 0.f, 0.f};

        if (isL0) {
          if (half == 0) {
            kloop<NKC0H, NKC0H, COH>(Hr0, Xp, o1, o1, Bsh, lane, acc);
          } else {
#pragma unroll
            for (int mf = 0; mf < 2; ++mf)
              xo[mf] = ((size_t)p * 256 + wv * 32 + mf * 16 + lr) * EPAD + lk;
            kloop<NKC0H, SPL0, COH>(Hr0 + 1088, Xp, o1, xo, Bsh, lane, acc);
          }
        } else {
          const f16* Ab = half ? Hr1 : Hr0;
          kloop<NKC1H, NKC1H, COH>(Ab, Ab, o1, o1, Bsh, lane, acc);
        }

        // ---- pair combine ----
        if (iswriter) {
#pragma unroll
          for (int mf = 0; mf < 2; ++mf)
#pragma unroll
            for (int nf = 0; nf < 2; ++nf)
              stg16f_coh(mybuf + ((size_t)(wvh * 64 + lane) * 4 + (mf * 2 + nf)) * 4,
                         acc[mf][nf]);
          vdrain();                              // partials at coherence point
        }
        __syncthreads();
        if (tid == 0)
          __hip_atomic_store(&flags2[bid], p + 1, __ATOMIC_RELAXED,
                             __HIP_MEMORY_SCOPE_AGENT);
        if (!iswriter) {
          while (__hip_atomic_load(&flags2[bid ^ 1], __ATOMIC_RELAXED,
                                   __HIP_MEMORY_SCOPE_AGENT) < p + 1)
            __builtin_amdgcn_s_sleep(1);
          f32x4 p00 = ldg16f_coh(pbuf + ((size_t)(wvh * 64 + lane) * 4 + 0) * 4);
          f32x4 p10 = ldg16f_coh(pbuf + ((size_t)(wvh * 64 + lane) * 4 + 2) * 4);
          f32x4 p01 = ldg16f_coh(pbuf + ((size_t)(wvh * 64 + lane) * 4 + 1) * 4);
          f32x4 p11 = ldg16f_coh(pbuf + ((size_t)(wvh * 64 + lane) * 4 + 3) * 4);
          vwp0(p00, p10, p01, p11);
          acc[0][0] += p00; acc[1][0] += p10; acc[0][1] += p01; acc[1][1] += p11;
          // bias + tanh + h store (16 write-through 2B stores)
#pragma unroll
          for (int nf = 0; nf < 2; ++nf) {
            const float bv = bias[n0 + nf * 16 + lr];
#pragma unroll
            for (int mf = 0; mf < 2; ++mf) {
              const int rb = wv * 32 + mf * 16 + hi * 4;
#pragma unroll
              for (int r = 0; r < 4; ++r)
                stg2_coh(Hw + (size_t)(rb + r) * 2048 + n0 + nf * 16 + lr,
                         (f16)tanh_fast(acc[mf][nf][r] + bv));
            }
          }
        }
      } else {
        // L1 @ p=0: h1[-1] = 0 (slot already memset; store anyway, harmless)
        if (!iswriter) {
#pragma unroll
          for (int nf = 0; nf < 2; ++nf)
#pragma unroll
            for (int mf = 0; mf < 2; ++mf) {
              const int rb = wv * 32 + mf * 16 + hi * 4;
#pragma unroll
              for (int r = 0; r < 4; ++r)
                stg2_coh(Hw + (size_t)(rb + r) * 2048 + n0 + nf * 16 + lr, (f16)0.f);
            }
        }
      }
    }
    if (p < 80) gbar(flags, p + 1);
  }
}

// ---------------------------------------------------------------------------
// epilogue: logits = sigmoid(h1[79] @ Wo + bo) -> 256 fp32
// ---------------------------------------------------------------------------
__global__ __launch_bounds__(256) void logits_k(
    const f16* __restrict__ h1, const float* __restrict__ Wo,
    const float* __restrict__ bo, float* __restrict__ out)
{
  int row = blockIdx.x * 4 + (threadIdx.x >> 6);
  int lane = threadIdx.x & 63;
  const f16* hr = h1 + (size_t)row * 2048;
  float s = 0.f;
#pragma unroll
  for (int it = 0; it < 4; ++it) {
    int k = it * 512 + lane * 8;
    f16x8 hv = *(const f16x8*)(hr + k);
    const float4* wp = (const float4*)(Wo + k);
    float4 w0 = wp[0], w1 = wp[1];
    s += (float)hv[0] * w0.x + (float)hv[1] * w0.y + (float)hv[2] * w0.z + (float)hv[3] * w0.w;
    s += (float)hv[4] * w1.x + (float)hv[5] * w1.y + (float)hv[6] * w1.z + (float)hv[7] * w1.w;
  }
#pragma unroll
  for (int off = 32; off > 0; off >>= 1) s += __shfl_down(s, off);
  if (lane == 0) out[row] = 1.f / (1.f + __expf(-(s + bo[0])));
}

// ---------------------------------------------------------------------------
extern "C" void kernel_launch(void* const* d_in, const int* in_sizes, int n_in,
                              void* d_out, int out_size, void* d_ws, size_t ws_size,
                              hipStream_t stream)
{
  (void)in_sizes; (void)n_in; (void)out_size;
  const int*   inputs = (const int*)d_in[0];
  const float* emb    = (const float*)d_in[1];
  const float* W0     = (const float*)d_in[2];
  const float* U0     = (const float*)d_in[3];
  const float* b0     = (const float*)d_in[4];
  const float* W1     = (const float*)d_in[5];
  const float* U1     = (const float*)d_in[6];
  const float* b1     = (const float*)d_in[7];
  const float* Wo     = (const float*)d_in[8];
  const float* bo     = (const float*)d_in[9];
  char* ws = (char*)d_ws;
  if (ws_size < WS_MIN) return;   // visible validation failure if too small

  const bool full = (ws_size >= WS_FULL);
  const int  nbuf = full ? 81 : 3;

  // zero barrier + pair flags, and the two t=-1 init slots
  hipMemsetAsync(ws + FLAGS_OFF, 0, 8192, stream);
  hipMemsetAsync(ws + H0_OFF, 0, HSLOT, stream);
  hipMemsetAsync(ws + H0_OFF + (size_t)nbuf * HSLOT, 0, HSLOT, stream);

  fmt_weights<<<6272, 256, 0, stream>>>(W0, U0, W1, U1, ws);
  embed_k<<<5120, 256, 0, stream>>>(inputs, emb, ws);
  if (full) rnn_persist<81, false><<<NWG, 512, 0, stream>>>(b0, b1, ws);
  else      rnn_persist<3,  true ><<<NWG, 512, 0, stream>>>(b0, b1, ws);

  const f16* h1f = (const f16*)(ws + H0_OFF) + (size_t)nbuf * HSLOT_H
                   + (size_t)(80 % nbuf) * HSLOT_H;
  logits_k<<<64, 256, 0, stream>>>(h1f, Wo, bo, (float*)d_out);
}